// Round 1
// baseline (1018.335 us; speedup 1.0000x reference)
//
#include <hip/hip_runtime.h>

#define NBATCH 8

// ---------------------------------------------------------------------------
// Face kernel: one thread per face. Computes cotangent weights per the
// reference (Heron's formula, EPS guard, A==0 -> 0) and scatter-adds the
// symmetric Laplacian contributions with float atomics.
// ---------------------------------------------------------------------------
__global__ void __launch_bounds__(256) cot_face_kernel(
    const float* __restrict__ V,   // (B*N*3)
    const int*   __restrict__ F,   // (B*Fc*3) int32
    float*       __restrict__ acc, // (B*N*3) zero-initialized accumulator (= d_out)
    float*       __restrict__ deg, // (B*N)   zero-initialized degree
    int N, int Fc)
{
    const float EPSf = 1e-10f;
    int total = NBATCH * Fc;
    int idx = blockIdx.x * blockDim.x + threadIdx.x;
    if (idx >= total) return;

    int b = idx / Fc;
    size_t f3 = (size_t)idx * 3;
    int i0 = F[f3 + 0];
    int i1 = F[f3 + 1];
    int i2 = F[f3 + 2];
    int vb = b * N;
    int g0 = vb + i0, g1 = vb + i1, g2 = vb + i2;

    const float* P0 = V + (size_t)g0 * 3;
    const float* P1 = V + (size_t)g1 * 3;
    const float* P2 = V + (size_t)g2 * 3;
    float x0 = P0[0], y0 = P0[1], z0 = P0[2];
    float x1 = P1[0], y1 = P1[1], z1 = P1[2];
    float x2 = P2[0], y2 = P2[1], z2 = P2[2];

    // Edge lengths, matching the reference exactly (sqrt then re-square).
    float dx, dy, dz;
    dx = x1 - x2; dy = y1 - y2; dz = z1 - z2;
    float l1 = sqrtf(dx * dx + dy * dy + dz * dz);   // |v2 - v3|
    dx = x2 - x0; dy = y2 - y0; dz = z2 - z0;
    float l2 = sqrtf(dx * dx + dy * dy + dz * dz);   // |v3 - v1|
    dx = x0 - x1; dy = y0 - y1; dz = z0 - z1;
    float l3 = sqrtf(dx * dx + dy * dy + dz * dz);   // |v1 - v2|

    float sp = (l1 + l2 + l3) * 0.5f;
    float inside = sp * (sp - l1) * (sp - l2) * (sp - l3);
    inside = fmaxf(inside, 0.0f);
    float A = 2.0f * sqrtf(inside);
    float denom = A + EPSf;

    float l1s = l1 * l1, l2s = l2 * l2, l3s = l3 * l3;
    // C = (...)/ (A+EPS) / 4 ; division by 4 is exact -> *0.25f
    float w0 = (l2s + l3s - l1s) / denom * 0.25f;  // edge (v2,v3): row g1, col g2
    float w1 = (l1s + l3s - l2s) / denom * 0.25f;  // edge (v3,v1): row g2, col g0
    float w2 = (l1s + l2s - l3s) / denom * 0.25f;  // edge (v1,v2): row g0, col g1
    if (A == 0.0f) { w0 = 0.0f; w1 = 0.0f; w2 = 0.0f; }

    // out[g0] += w1*P2 + w2*P1
    atomicAdd(&acc[(size_t)g0 * 3 + 0], w1 * x2 + w2 * x1);
    atomicAdd(&acc[(size_t)g0 * 3 + 1], w1 * y2 + w2 * y1);
    atomicAdd(&acc[(size_t)g0 * 3 + 2], w1 * z2 + w2 * z1);
    // out[g1] += w0*P2 + w2*P0
    atomicAdd(&acc[(size_t)g1 * 3 + 0], w0 * x2 + w2 * x0);
    atomicAdd(&acc[(size_t)g1 * 3 + 1], w0 * y2 + w2 * y0);
    atomicAdd(&acc[(size_t)g1 * 3 + 2], w0 * z2 + w2 * z0);
    // out[g2] += w0*P1 + w1*P0
    atomicAdd(&acc[(size_t)g2 * 3 + 0], w0 * x1 + w1 * x0);
    atomicAdd(&acc[(size_t)g2 * 3 + 1], w0 * y1 + w1 * y0);
    atomicAdd(&acc[(size_t)g2 * 3 + 2], w0 * z1 + w1 * z0);
    // degrees
    atomicAdd(&deg[g0], w1 + w2);
    atomicAdd(&deg[g1], w0 + w2);
    atomicAdd(&deg[g2], w0 + w1);
}

// ---------------------------------------------------------------------------
// Finalize: out = acc - deg * V  (one thread per vertex)
// ---------------------------------------------------------------------------
__global__ void __launch_bounds__(256) cot_finalize_kernel(
    const float* __restrict__ V,
    const float* __restrict__ deg,
    float*       __restrict__ out,
    int BN)
{
    int i = blockIdx.x * blockDim.x + threadIdx.x;
    if (i >= BN) return;
    float d = deg[i];
    size_t o = (size_t)i * 3;
    out[o + 0] = out[o + 0] - d * V[o + 0];
    out[o + 1] = out[o + 1] - d * V[o + 1];
    out[o + 2] = out[o + 2] - d * V[o + 2];
}

extern "C" void kernel_launch(void* const* d_in, const int* in_sizes, int n_in,
                              void* d_out, int out_size, void* d_ws, size_t ws_size,
                              hipStream_t stream) {
    const float* V = (const float*)d_in[0];
    const int*   F = (const int*)d_in[1];
    float* out = (float*)d_out;
    float* deg = (float*)d_ws;   // BN floats of scratch for the degree vector

    int BN3 = in_sizes[0];            // B*N*3
    int N   = BN3 / (NBATCH * 3);
    int Fc  = in_sizes[1] / (NBATCH * 3);
    int BN  = NBATCH * N;

    // Accumulators are poisoned (0xAA) before every timed launch -> zero them.
    hipMemsetAsync(d_out, 0, (size_t)BN3 * sizeof(float), stream);
    hipMemsetAsync(d_ws,  0, (size_t)BN  * sizeof(float), stream);

    int totalF = NBATCH * Fc;
    int fblocks = (totalF + 255) / 256;
    cot_face_kernel<<<fblocks, 256, 0, stream>>>(V, F, out, deg, N, Fc);

    int vblocks = (BN + 255) / 256;
    cot_finalize_kernel<<<vblocks, 256, 0, stream>>>(V, deg, out, BN);
}

// Round 2
// 710.511 us; speedup vs baseline: 1.4332x; 1.4332x over previous
//
#include <hip/hip_runtime.h>

#define NBATCH 8

// ---------------------------------------------------------------------------
// 64-bit CAS-based packed float2 atomic add: adds (ax, ay) to two adjacent
// floats. One fabric atomic per op instead of two. `seed` is a (possibly
// stale) preloaded value of *addr used for the first attempt; staleness only
// costs one extra CAS iteration.
// ---------------------------------------------------------------------------
__device__ __forceinline__ void atomic_add_f2(unsigned long long* addr,
                                              unsigned long long seed,
                                              float ax, float ay) {
    unsigned long long old = seed;
    while (true) {
        float lo = __uint_as_float((unsigned)(old & 0xffffffffull));
        float hi = __uint_as_float((unsigned)(old >> 32));
        lo += ax; hi += ay;
        unsigned long long nv =
            ((unsigned long long)__float_as_uint(hi) << 32) | (unsigned long long)__float_as_uint(lo);
        unsigned long long ret = atomicCAS(addr, old, nv);
        if (ret == old) break;
        old = ret;
    }
}

// ---------------------------------------------------------------------------
// Path A face kernel: accumulator is float4-stride (x,y,z,pad) per vertex in
// d_ws. Degree is folded: contribution to vertex a is w_b*(Pb - Pa) + ...,
// so out = acc directly (no finalize). 6 atomic ops per face (3x CAS64 + 3x f32).
// ---------------------------------------------------------------------------
__global__ void __launch_bounds__(256) cot_face_cas(
    const float* __restrict__ V,   // (B*N*3)
    const int*   __restrict__ F,   // (B*Fc*3)
    char*        __restrict__ acc, // (B*N) * 16B {x,y,z,pad}
    int N, int Fc)
{
    const float EPSf = 1e-10f;
    int total = NBATCH * Fc;
    int idx = blockIdx.x * blockDim.x + threadIdx.x;
    if (idx >= total) return;

    int b = idx / Fc;
    size_t f3 = (size_t)idx * 3;
    int i0 = F[f3 + 0];
    int i1 = F[f3 + 1];
    int i2 = F[f3 + 2];
    int vb = b * N;
    int g0 = vb + i0, g1 = vb + i1, g2 = vb + i2;

    unsigned long long* xy0 = (unsigned long long*)(acc + (size_t)g0 * 16);
    unsigned long long* xy1 = (unsigned long long*)(acc + (size_t)g1 * 16);
    unsigned long long* xy2 = (unsigned long long*)(acc + (size_t)g2 * 16);
    // Preload current (x,y) pairs early to overlap latency with the geometry
    // math below; stale seeds just cost one extra CAS iteration.
    unsigned long long s0 = *(volatile unsigned long long*)xy0;
    unsigned long long s1 = *(volatile unsigned long long*)xy1;
    unsigned long long s2 = *(volatile unsigned long long*)xy2;

    const float* P0 = V + (size_t)g0 * 3;
    const float* P1 = V + (size_t)g1 * 3;
    const float* P2 = V + (size_t)g2 * 3;
    float x0 = P0[0], y0 = P0[1], z0 = P0[2];
    float x1 = P1[0], y1 = P1[1], z1 = P1[2];
    float x2 = P2[0], y2 = P2[1], z2 = P2[2];

    float dx, dy, dz;
    dx = x1 - x2; dy = y1 - y2; dz = z1 - z2;
    float l1 = sqrtf(dx * dx + dy * dy + dz * dz);   // |v2 - v3|
    dx = x2 - x0; dy = y2 - y0; dz = z2 - z0;
    float l2 = sqrtf(dx * dx + dy * dy + dz * dz);   // |v3 - v1|
    dx = x0 - x1; dy = y0 - y1; dz = z0 - z1;
    float l3 = sqrtf(dx * dx + dy * dy + dz * dz);   // |v1 - v2|

    float sp = (l1 + l2 + l3) * 0.5f;
    float inside = sp * (sp - l1) * (sp - l2) * (sp - l3);
    inside = fmaxf(inside, 0.0f);
    float A = 2.0f * sqrtf(inside);
    float denom = A + EPSf;

    float l1s = l1 * l1, l2s = l2 * l2, l3s = l3 * l3;
    float w0 = (l2s + l3s - l1s) / denom * 0.25f;  // edge (v2,v3)
    float w1 = (l1s + l3s - l2s) / denom * 0.25f;  // edge (v3,v1)
    float w2 = (l1s + l2s - l3s) / denom * 0.25f;  // edge (v1,v2)
    if (A == 0.0f) { w0 = 0.0f; w1 = 0.0f; w2 = 0.0f; }

    // Degree-folded contributions: c(a) = w_ab*(Pb - Pa) + w_ac*(Pc - Pa)
    float c0x = w1 * (x2 - x0) + w2 * (x1 - x0);
    float c0y = w1 * (y2 - y0) + w2 * (y1 - y0);
    float c0z = w1 * (z2 - z0) + w2 * (z1 - z0);
    float c1x = w0 * (x2 - x1) + w2 * (x0 - x1);
    float c1y = w0 * (y2 - y1) + w2 * (y0 - y1);
    float c1z = w0 * (z2 - z1) + w2 * (z0 - z1);
    float c2x = w0 * (x1 - x2) + w1 * (x0 - x2);
    float c2y = w0 * (y1 - y2) + w1 * (y0 - y2);
    float c2z = w0 * (z1 - z2) + w1 * (z0 - z2);

    atomic_add_f2(xy0, s0, c0x, c0y);
    atomic_add_f2(xy1, s1, c1x, c1y);
    atomic_add_f2(xy2, s2, c2x, c2y);
    atomicAdd((float*)(acc + (size_t)g0 * 16 + 8), c0z);
    atomicAdd((float*)(acc + (size_t)g1 * 16 + 8), c1z);
    atomicAdd((float*)(acc + (size_t)g2 * 16 + 8), c2z);
}

// Repack float4-stride accumulator -> (BN,3) output.
__global__ void __launch_bounds__(256) cot_repack(
    const float4* __restrict__ acc,
    float*        __restrict__ out,
    int BN)
{
    int v = blockIdx.x * blockDim.x + threadIdx.x;
    if (v >= BN) return;
    float4 a = acc[v];
    size_t o = (size_t)v * 3;
    out[o + 0] = a.x;
    out[o + 1] = a.y;
    out[o + 2] = a.z;
}

// ---------------------------------------------------------------------------
// Path B (fallback if ws too small): degree-folded, 9 float atomics per face
// straight into d_out (stride 3).
// ---------------------------------------------------------------------------
__global__ void __launch_bounds__(256) cot_face_add9(
    const float* __restrict__ V,
    const int*   __restrict__ F,
    float*       __restrict__ out, // (B*N*3) zeroed
    int N, int Fc)
{
    const float EPSf = 1e-10f;
    int total = NBATCH * Fc;
    int idx = blockIdx.x * blockDim.x + threadIdx.x;
    if (idx >= total) return;

    int b = idx / Fc;
    size_t f3 = (size_t)idx * 3;
    int i0 = F[f3 + 0];
    int i1 = F[f3 + 1];
    int i2 = F[f3 + 2];
    int vb = b * N;
    int g0 = vb + i0, g1 = vb + i1, g2 = vb + i2;

    const float* P0 = V + (size_t)g0 * 3;
    const float* P1 = V + (size_t)g1 * 3;
    const float* P2 = V + (size_t)g2 * 3;
    float x0 = P0[0], y0 = P0[1], z0 = P0[2];
    float x1 = P1[0], y1 = P1[1], z1 = P1[2];
    float x2 = P2[0], y2 = P2[1], z2 = P2[2];

    float dx, dy, dz;
    dx = x1 - x2; dy = y1 - y2; dz = z1 - z2;
    float l1 = sqrtf(dx * dx + dy * dy + dz * dz);
    dx = x2 - x0; dy = y2 - y0; dz = z2 - z0;
    float l2 = sqrtf(dx * dx + dy * dy + dz * dz);
    dx = x0 - x1; dy = y0 - y1; dz = z0 - z1;
    float l3 = sqrtf(dx * dx + dy * dy + dz * dz);

    float sp = (l1 + l2 + l3) * 0.5f;
    float inside = sp * (sp - l1) * (sp - l2) * (sp - l3);
    inside = fmaxf(inside, 0.0f);
    float A = 2.0f * sqrtf(inside);
    float denom = A + EPSf;

    float l1s = l1 * l1, l2s = l2 * l2, l3s = l3 * l3;
    float w0 = (l2s + l3s - l1s) / denom * 0.25f;
    float w1 = (l1s + l3s - l2s) / denom * 0.25f;
    float w2 = (l1s + l2s - l3s) / denom * 0.25f;
    if (A == 0.0f) { w0 = 0.0f; w1 = 0.0f; w2 = 0.0f; }

    atomicAdd(&out[(size_t)g0 * 3 + 0], w1 * (x2 - x0) + w2 * (x1 - x0));
    atomicAdd(&out[(size_t)g0 * 3 + 1], w1 * (y2 - y0) + w2 * (y1 - y0));
    atomicAdd(&out[(size_t)g0 * 3 + 2], w1 * (z2 - z0) + w2 * (z1 - z0));
    atomicAdd(&out[(size_t)g1 * 3 + 0], w0 * (x2 - x1) + w2 * (x0 - x1));
    atomicAdd(&out[(size_t)g1 * 3 + 1], w0 * (y2 - y1) + w2 * (y0 - y1));
    atomicAdd(&out[(size_t)g1 * 3 + 2], w0 * (z2 - z1) + w2 * (z0 - z1));
    atomicAdd(&out[(size_t)g2 * 3 + 0], w0 * (x1 - x2) + w1 * (x0 - x2));
    atomicAdd(&out[(size_t)g2 * 3 + 1], w0 * (y1 - y2) + w1 * (y0 - y2));
    atomicAdd(&out[(size_t)g2 * 3 + 2], w0 * (z1 - z2) + w1 * (z0 - z2));
}

extern "C" void kernel_launch(void* const* d_in, const int* in_sizes, int n_in,
                              void* d_out, int out_size, void* d_ws, size_t ws_size,
                              hipStream_t stream) {
    const float* V = (const float*)d_in[0];
    const int*   F = (const int*)d_in[1];
    float* out = (float*)d_out;

    int BN3 = in_sizes[0];            // B*N*3
    int N   = BN3 / (NBATCH * 3);
    int Fc  = in_sizes[1] / (NBATCH * 3);
    int BN  = NBATCH * N;

    int totalF = NBATCH * Fc;
    int fblocks = (totalF + 255) / 256;
    int vblocks = (BN + 255) / 256;

    size_t need = (size_t)BN * 16;
    if (ws_size >= need) {
        // Path A: packed CAS accumulation in ws, then repack.
        hipMemsetAsync(d_ws, 0, need, stream);
        cot_face_cas<<<fblocks, 256, 0, stream>>>(V, F, (char*)d_ws, N, Fc);
        cot_repack<<<vblocks, 256, 0, stream>>>((const float4*)d_ws, out, BN);
    } else {
        // Path B: 9 plain float atomics into d_out.
        hipMemsetAsync(d_out, 0, (size_t)BN3 * sizeof(float), stream);
        cot_face_add9<<<fblocks, 256, 0, stream>>>(V, F, out, N, Fc);
    }
}